// Round 1
// baseline (49.811 us; speedup 1.0000x reference)
//
#include <hip/hip_runtime.h>
#include <math.h>

// Problem constants (from reference setup_inputs)
#define BATCH 16
#define HIN   224
#define WIN   224
#define CCH   32
#define FDIM  128
#define HOUT  224
#define WOUT  224

// ---------------- Kernel 1: theta = tanh(theta_feat @ W + b) ----------------
// 16 batches x 6 outputs = 96 independent length-128 dot products.
__global__ void st_theta_kernel(const float* __restrict__ tf,
                                const float* __restrict__ Wm,
                                const float* __restrict__ bv,
                                float* __restrict__ theta) {
    int t = blockIdx.x * blockDim.x + threadIdx.x;
    if (t >= BATCH * 6) return;
    int bi = t / 6;
    int j  = t - bi * 6;
    float acc = bv[j];
    const float* row = tf + bi * FDIM;
#pragma unroll 8
    for (int k = 0; k < FDIM; ++k) {
        acc += row[k] * Wm[k * 6 + j];
    }
    theta[t] = tanhf(acc);
}

// ---------------- Kernel 2: bilinear sampling ----------------
// One thread per (pixel, float4-of-channels). 8 threads per output pixel.
__global__ __launch_bounds__(256) void st_sample_kernel(const float* __restrict__ im,
                                                        const float* __restrict__ theta,
                                                        float* __restrict__ out) {
    int gid = blockIdx.x * blockDim.x + threadIdx.x;
    // total = BATCH*HOUT*WOUT*8 exactly divisible by 256, no guard needed,
    // but keep one for safety.
    if (gid >= BATCH * HOUT * WOUT * 8) return;

    int p  = gid >> 3;        // pixel index
    int c4 = gid & 7;         // which float4 of the 8 per pixel

    int b   = p / (HOUT * WOUT);
    int rem = p - b * (HOUT * WOUT);
    int ho  = rem / WOUT;
    int wo  = rem - ho * WOUT;

    // linspace(-1,1,N): value i = -1 + 2*i/(N-1)
    float x_t = -1.0f + (2.0f * (float)wo) / (float)(WOUT - 1);
    float y_t = -1.0f + (2.0f * (float)ho) / (float)(HOUT - 1);

    const float* th = theta + b * 6;
    float t0 = th[0], t1 = th[1], t2 = th[2];
    float t3 = th[3], t4 = th[4], t5 = th[5];

    float xs = t0 * x_t + t1 * y_t + t2;
    float ys = t3 * x_t + t4 * y_t + t5;

    float xp = (xs + 1.0f) * (0.5f * (float)WIN);
    float yp = (ys + 1.0f) * (0.5f * (float)HIN);

    float fx0 = floorf(xp);
    float fy0 = floorf(yp);
    int x0 = (int)fx0;
    int y0 = (int)fy0;
    int x1 = x0 + 1;
    int y1 = y0 + 1;

    // clip (reference clips the int coords, then uses the clipped floats in weights)
    x0 = min(max(x0, 0), WIN - 1);
    x1 = min(max(x1, 0), WIN - 1);
    y0 = min(max(y0, 0), HIN - 1);
    y1 = min(max(y1, 0), HIN - 1);

    float x0f = (float)x0, x1f = (float)x1;
    float y0f = (float)y0, y1f = (float)y1;

    float wa = (x1f - xp) * (y1f - yp);
    float wb = (x1f - xp) * (yp - y0f);
    float wc = (xp - x0f) * (y1f - yp);
    float wd = (xp - x0f) * (yp - y0f);

    const float4* imf4 = (const float4*)im;
    size_t base = (size_t)b * (size_t)(HIN * WIN * 8);

    float4 Ia = imf4[base + ((size_t)(y0 * WIN + x0)) * 8 + c4];
    float4 Ib = imf4[base + ((size_t)(y1 * WIN + x0)) * 8 + c4];
    float4 Ic = imf4[base + ((size_t)(y0 * WIN + x1)) * 8 + c4];
    float4 Id = imf4[base + ((size_t)(y1 * WIN + x1)) * 8 + c4];

    float4 o;
    o.x = wa * Ia.x + wb * Ib.x + wc * Ic.x + wd * Id.x;
    o.y = wa * Ia.y + wb * Ib.y + wc * Ic.y + wd * Id.y;
    o.z = wa * Ia.z + wb * Ib.z + wc * Ic.z + wd * Id.z;
    o.w = wa * Ia.w + wb * Ib.w + wc * Ic.w + wd * Id.w;

    ((float4*)out)[gid] = o;
}

extern "C" void kernel_launch(void* const* d_in, const int* in_sizes, int n_in,
                              void* d_out, int out_size, void* d_ws, size_t ws_size,
                              hipStream_t stream) {
    const float* x  = (const float*)d_in[0];   // (16,224,224,32) f32
    const float* tf = (const float*)d_in[1];   // (16,128) f32
    const float* Wm = (const float*)d_in[2];   // (128,6) f32
    const float* bv = (const float*)d_in[3];   // (6,) f32
    float* out = (float*)d_out;                // (16,224,224,32) f32

    float* theta = (float*)d_ws;               // 96 floats

    st_theta_kernel<<<1, 128, 0, stream>>>(tf, Wm, bv, theta);

    int total = BATCH * HOUT * WOUT * 8;       // 6,422,528 threads
    int block = 256;
    int grid  = (total + block - 1) / block;   // 25088 blocks
    st_sample_kernel<<<grid, block, 0, stream>>>(x, theta, out);
}